// Round 8
// baseline (335.429 us; speedup 1.0000x reference)
//
#include <hip/hip_runtime.h>
#include <hip/hip_fp16.h>

// GCN 2-layer GraphConv (norm='both'), fp32 in/out, fp16 intermediates.
// Round 8: round-7 structure with the EXEC-mask shfl bug fixed — __shfl is
//          hoisted OUT of the divergent gather branch (ds_bpermute reads
//          from inactive source lanes are undefined; shfl must be wave-uniform).
//
// ws: int hist_s[N] | hist_d[N](=deg) | rowptr[N] | bsum[1024] | col[E] | rank[E]
//     float in_norm[N]
//     half h1[64N] | h2[32N]

#define SCAN_BLK 1024

// ---- K1: hist_d + rank (interleaved blocks) || h1 = x @ W1 unscaled ----
__global__ __launch_bounds__(256) void k1_histd_xw1(
    const int* __restrict__ dst, int* __restrict__ hist_d, int* __restrict__ rank,
    const float* __restrict__ x, const float* __restrict__ W,
    __half* __restrict__ h1, int E, int n, int GH, int GX) {
  __shared__ float Ws[64 * 64];
  __shared__ float xs[16 * 64];
  int bid = blockIdx.x;
  int Mn = (GH < GX) ? GH : GX;
  bool isHist;
  int idx;
  if (bid < 2 * Mn) { isHist = !(bid & 1); idx = bid >> 1; }
  else               { isHist = (GH > GX); idx = bid - 2 * Mn + Mn; }

  if (isHist) {
    int e = idx * 256 + threadIdx.x;
    if (e < E) rank[e] = atomicAdd(&hist_d[dst[e]], 1);
    return;
  }
  int t = threadIdx.x;
#pragma unroll
  for (int i = 0; i < 16; i++) Ws[i * 256 + t] = W[i * 256 + t];
  int row0 = idx * 16;
#pragma unroll
  for (int i = 0; i < 4; i++) {
    int gi = i * 256 + t;
    int r = gi >> 6, k = gi & 63;
    int row = row0 + r;
    xs[gi] = (row < n) ? x[row * 64 + k] : 0.0f;
  }
  __syncthreads();
  int c = t & 63, rq = t >> 6;
  float acc[4] = {0.f, 0.f, 0.f, 0.f};
#pragma unroll 16
  for (int k = 0; k < 64; k++) {
    float w = Ws[k * 64 + c];
#pragma unroll
    for (int rr = 0; rr < 4; rr++) acc[rr] += xs[(rq + rr * 4) * 64 + k] * w;
  }
#pragma unroll
  for (int rr = 0; rr < 4; rr++) {
    int row = row0 + rq + rr * 4;
    if (row < n) h1[(size_t)row * 64 + c] = __float2half(acc[rr]);
  }
}

// ---- scan of hist_d -> rowptr, fused in_norm ----
__global__ __launch_bounds__(256) void scan_local(const int* __restrict__ hist_d,
                                                  int* __restrict__ rowptr,
                                                  int* __restrict__ bsum,
                                                  float* __restrict__ in_norm, int n) {
  __shared__ int tmp[256];
  int t = threadIdx.x;
  int base = blockIdx.x * SCAN_BLK + t * 4;
  int v[4], s = 0;
#pragma unroll
  for (int i = 0; i < 4; i++) {
    v[i] = (base + i < n) ? hist_d[base + i] : 0;
    s += v[i];
  }
#pragma unroll
  for (int i = 0; i < 4; i++)
    if (base + i < n) in_norm[base + i] = rsqrtf(fmaxf((float)v[i], 1.0f));
  tmp[t] = s;
  __syncthreads();
#pragma unroll
  for (int off = 1; off < 256; off <<= 1) {
    int val = (t >= off) ? tmp[t - off] : 0;
    __syncthreads();
    tmp[t] += val;
    __syncthreads();
  }
  int run = tmp[t] - s;
#pragma unroll
  for (int i = 0; i < 4; i++) {
    if (base + i < n) rowptr[base + i] = run;
    run += v[i];
  }
  if (t == 255) bsum[blockIdx.x] = tmp[255];
}

__global__ __launch_bounds__(128) void scan_bsums(int* __restrict__ bsum, int nb) {
  __shared__ int tmp[128];
  int t = threadIdx.x;
  int v = (t < nb) ? bsum[t] : 0;
  tmp[t] = v;
  __syncthreads();
#pragma unroll
  for (int off = 1; off < 128; off <<= 1) {
    int val = (t >= off) ? tmp[t - off] : 0;
    __syncthreads();
    tmp[t] += val;
    __syncthreads();
  }
  if (t < nb) bsum[t] = tmp[t] - v;
}

__global__ __launch_bounds__(256) void scan_add(int* __restrict__ out,
                                                const int* __restrict__ bsum, int n) {
  int i = blockIdx.x * 256 + threadIdx.x;
  if (i < n) out[i] += bsum[i / SCAN_BLK];
}

// ---- K2: hist_s atomics || CSR placement (place hides in atomic shadow) ----
__global__ __launch_bounds__(256) void k2_hists_place(
    const int* __restrict__ src, const int* __restrict__ dst,
    const int* __restrict__ rowptr, const int* __restrict__ rank,
    int* __restrict__ hist_s, int* __restrict__ col, int E) {
  int e = blockIdx.x * 256 + threadIdx.x;
  if (e < E) {
    int s = src[e];
    atomicAdd(&hist_s[s], 1);
    col[rowptr[dst[e]] + rank[e]] = s;
  }
}

__device__ inline void acc8h(float* a, uint4 r, float nn) {
  const __half2* hp = reinterpret_cast<const __half2*>(&r);
#pragma unroll
  for (int i = 0; i < 4; i++) {
    float2 f = __half22float2(hp[i]);
    a[2 * i] += nn * f.x;
    a[2 * i + 1] += nn * f.y;
  }
}

// ---- pull64 + fused xw2 ----
// wave w = node; lane: sub = l>>3 (8 edge slots), fq = l&7 (16B of 128B row).
// Per 64-edge chunk: ONE coalesced col load; __shfl done wave-uniform (all
// lanes active — EXEC-mask safe), then masked independent gathers.
__global__ __launch_bounds__(256) void pull64_xw2(
    const int* __restrict__ rowptr, const int* __restrict__ deg,
    const int* __restrict__ col, const __half* __restrict__ h1,
    const int* __restrict__ hist_s, const float* __restrict__ in_norm,
    const float* __restrict__ b1, const float* __restrict__ W2,
    __half* __restrict__ h2, int n) {
  __shared__ float W2s[64 * 32];
  __shared__ float xrow[4][64];
  int t = threadIdx.x;
#pragma unroll
  for (int i = 0; i < 8; i++) W2s[i * 256 + t] = W2[i * 256 + t];

  int w = t >> 6;
  int node = blockIdx.x * 4 + w;
  int l = t & 63;
  int sub = l >> 3, fq = l & 7;

  if (node < n) {
    int beg = rowptr[node];
    int end = beg + deg[node];
    float acc[8] = {0, 0, 0, 0, 0, 0, 0, 0};
    for (int base = beg; base < end; base += 64) {
      int cj = base + l;
      int colv = (cj < end) ? col[cj] : 0;  // one coalesced 64-index load
#pragma unroll
      for (int r = 0; r < 8; r++) {
        int s = __shfl(colv, r * 8 + sub);  // wave-uniform: all source lanes active
        int jj = base + r * 8 + sub;
        if (jj < end) {
          float nn = rsqrtf(fmaxf((float)hist_s[s], 1.0f));
          uint4 rv = ((const uint4*)h1)[(size_t)s * 8 + fq];
          acc8h(acc, rv, nn);
        }
      }
    }
#pragma unroll
    for (int d = 8; d <= 32; d <<= 1) {
#pragma unroll
      for (int i = 0; i < 8; i++) acc[i] += __shfl_xor(acc[i], d);
    }
    if (sub == 0) {
      float innv = in_norm[node];
      float onnv = rsqrtf(fmaxf((float)hist_s[node], 1.0f));
      float4 ba = ((const float4*)b1)[fq * 2];
      float4 bb = ((const float4*)b1)[fq * 2 + 1];
      float bv[8] = {ba.x, ba.y, ba.z, ba.w, bb.x, bb.y, bb.z, bb.w};
#pragma unroll
      for (int i = 0; i < 8; i++)
        xrow[w][fq * 8 + i] = fmaxf(acc[i] * innv + bv[i], 0.0f) * onnv;
    }
  }
  __syncthreads();
  // phase 2: h2[node,32] = xrow @ W2  (threads 0..127)
  if (t < 128) {
    int w2 = t >> 5, c = t & 31;
    int nd = blockIdx.x * 4 + w2;
    if (nd < n) {
      float dot = 0.f;
#pragma unroll 16
      for (int k = 0; k < 64; k++) dot += xrow[w2][k] * W2s[k * 32 + c];
      h2[(size_t)nd * 32 + c] = __float2half(dot);
    }
  }
}

// ---- pull 32 feats + epilogue, same structure (shfl hoisted) ----
// sub = l>>3 (8 slots), fq = l&7 (8B of 64B row)
__global__ __launch_bounds__(256) void gcn_pull32(const int* __restrict__ rowptr,
                                                  const int* __restrict__ deg,
                                                  const int* __restrict__ col,
                                                  const __half* __restrict__ h,
                                                  const float* __restrict__ in_norm,
                                                  const float* __restrict__ b2,
                                                  float* __restrict__ out, int n) {
  int t = threadIdx.x;
  int node = blockIdx.x * 4 + (t >> 6);
  if (node >= n) return;
  int l = t & 63;
  int sub = l >> 3, fq = l & 7;
  int beg = rowptr[node];
  int end = beg + deg[node];
  float acc[4] = {0, 0, 0, 0};
  for (int base = beg; base < end; base += 64) {
    int cj = base + l;
    int colv = (cj < end) ? col[cj] : 0;
#pragma unroll
    for (int r = 0; r < 8; r++) {
      int s = __shfl(colv, r * 8 + sub);  // wave-uniform shfl
      int jj = base + r * 8 + sub;
      if (jj < end) {
        uint2 rv = ((const uint2*)h)[(size_t)s * 8 + fq];
        const __half2* p = reinterpret_cast<const __half2*>(&rv);
#pragma unroll
        for (int i = 0; i < 2; i++) {
          float2 f = __half22float2(p[i]);
          acc[2 * i] += f.x;
          acc[2 * i + 1] += f.y;
        }
      }
    }
  }
#pragma unroll
  for (int d = 8; d <= 32; d <<= 1) {
#pragma unroll
    for (int i = 0; i < 4; i++) acc[i] += __shfl_xor(acc[i], d);
  }
  if (sub == 0) {
    float s = in_norm[node];
    float4 bb = ((const float4*)b2)[fq];
    float4 o;
    o.x = acc[0] * s + bb.x;
    o.y = acc[1] * s + bb.y;
    o.z = acc[2] * s + bb.z;
    o.w = acc[3] * s + bb.w;
    ((float4*)out)[(size_t)node * 8 + fq] = o;
  }
}

extern "C" void kernel_launch(void* const* d_in, const int* in_sizes, int n_in,
                              void* d_out, int out_size, void* d_ws, size_t ws_size,
                              hipStream_t stream) {
  const float* x   = (const float*)d_in[0];
  const int*   src = (const int*)d_in[1];
  const int*   dst = (const int*)d_in[2];
  const float* W1  = (const float*)d_in[3];
  const float* b1  = (const float*)d_in[4];
  const float* W2  = (const float*)d_in[5];
  const float* b2  = (const float*)d_in[6];
  float* out = (float*)d_out;

  const int N = in_sizes[0] / 64;   // 100000
  const int E = in_sizes[1];        // 1600000
  const int NB = (N + SCAN_BLK - 1) / SCAN_BLK;

  int* hist_s = (int*)d_ws;                    // N
  int* hist_d = hist_s + N;                    // N (doubles as deg)
  int* rowptr = hist_d + N;                    // N
  int* bsum   = rowptr + N;                    // 1024
  int* col    = bsum + 1024;                   // E
  int* rank   = col + E;                       // E
  float* in_norm = (float*)(rank + E);         // N
  __half* h1  = (__half*)(in_norm + N);        // 64N halves
  __half* h2  = h1 + (size_t)64 * N;           // 32N halves

  hipMemsetAsync(hist_s, 0, (size_t)2 * N * sizeof(int), stream);

  int GH = (E + 255) / 256;
  int GX = (N + 15) / 16;
  k1_histd_xw1<<<GH + GX, 256, 0, stream>>>(dst, hist_d, rank, x, W1, h1, E, N, GH, GX);
  scan_local<<<NB, 256, 0, stream>>>(hist_d, rowptr, bsum, in_norm, N);
  scan_bsums<<<1, 128, 0, stream>>>(bsum, NB);
  scan_add<<<(N + 255) / 256, 256, 0, stream>>>(rowptr, bsum, N);
  k2_hists_place<<<GH, 256, 0, stream>>>(src, dst, rowptr, rank, hist_s, col, E);
  pull64_xw2<<<(N + 3) / 4, 256, 0, stream>>>(rowptr, hist_d, col, h1, hist_s,
                                              in_norm, b1, W2, h2, N);
  gcn_pull32<<<(N + 3) / 4, 256, 0, stream>>>(rowptr, hist_d, col, h2, in_norm, b2, out, N);
}